// Round 8
// baseline (82.837 us; speedup 1.0000x reference)
//
#include <hip/hip_runtime.h>
#include <hip/hip_bf16.h>

namespace {

constexpr int T = 5, F = 30, H = 20;
constexpr int BATCH = 131072;
constexpr int BPB = 64;     // batch rows per block (16 per wave)
constexpr int XSS = 36;     // xs row stride (dwords) inside slab
constexpr int HSS = 36;     // hb row stride
constexpr int SLAB = 1600;  // per-wave slab dwords: loop{xs[0,576)+hb[576,1152)} / drain{hist[16][100]}

typedef __attribute__((ext_vector_type(8))) short bf16x8;
typedef __attribute__((ext_vector_type(4))) float f32x4;

union FragU { __hip_bfloat162 h2[4]; unsigned u32[4]; bf16x8 v; };

__device__ __forceinline__ float sig(float v) {
  return __builtin_amdgcn_rcpf(1.0f + __builtin_amdgcn_exp2f(v * -1.44269504f));
}
// tanh(v) = 2*sigmoid(2v) - 1; saturates correctly at +-inf, no NaN paths.
__device__ __forceinline__ float tanh_s(float v) {
  return fmaf(2.0f,
              __builtin_amdgcn_rcpf(1.0f + __builtin_amdgcn_exp2f(v * -2.88539008f)),
              -1.0f);
}

// Barrier-free, wave-private slab. Lifetimes: xs/hb live during the t-loop,
// the SAME slab is reused as hist[16][100] at drain (program order within a
// wave is the only ordering needed; per-wave DS ops execute in order).
__global__ __launch_bounds__(256, 5) void lstm_slab(
    const float* __restrict__ x,
    const float* __restrict__ wf, const float* __restrict__ wi,
    const float* __restrict__ wo, const float* __restrict__ wc,
    const float* __restrict__ uf, const float* __restrict__ ui,
    const float* __restrict__ uo, const float* __restrict__ uc,
    const float* __restrict__ bf, const float* __restrict__ bi,
    const float* __restrict__ bo, const float* __restrict__ bc,
    float* __restrict__ out)
{
  const int tid  = threadIdx.x;
  const int lane = tid & 63;
  const int wv   = tid >> 6;
  const int r15  = lane & 15;
  const int q    = lane >> 4;
  const int b0   = blockIdx.x * BPB;
  const int w0   = 16 * wv;

  const float* xwave = x + (size_t)(b0 + w0) * (T * F);   // contiguous 9.6 KB
  float*       owave = out + (size_t)(b0 + w0) * (T * H); // contiguous 6.4 KB

  __shared__ __align__(16) float lds[4][SLAB];            // 25.6 KB total
  float* const slab = lds[wv];
  float* const xsl  = slab;          // [16][36]
  float* const hbl  = slab + 576;    // [16][36]

  // ---- A-side fragments. W rows hidx = 4*jj + gate; bias folded at k==30
  // (x virtual col 30 == 1.0; only even k0 can be 30).
  const int gA = r15 & 3;
  const int jA = r15 >> 2;
  const float* Wg = (gA == 0) ? wf : (gA == 1) ? wi : (gA == 2) ? wo : wc;
  const float* Ug = (gA == 0) ? uf : (gA == 1) ? ui : (gA == 2) ? uo : uc;
  const float* Bg = (gA == 0) ? bf : (gA == 1) ? bi : (gA == 2) ? bo : bc;

  bf16x8 wfrag[5], ufrag[5];
#pragma unroll
  for (int m = 0; m < 5; ++m) {
    const int jj = 4 * m + jA;
    FragU fw, fu;
#pragma unroll
    for (int e = 0; e < 4; ++e) {
      const int k0 = 8 * q + 2 * e, k1 = k0 + 1;
      float w0v = (k0 < F) ? Wg[k0 * H + jj] : (k0 == F ? Bg[jj] : 0.f);
      float w1v = (k1 < F) ? Wg[k1 * H + jj] : 0.f;
      fw.h2[e] = __float22bfloat162_rn(float2{w0v, w1v});
      float u0 = (k0 < H) ? Ug[k0 * H + jj] : 0.f;
      float u1 = (k1 < H) ? Ug[k1 * H + jj] : 0.f;
      fu.h2[e] = __float22bfloat162_rn(float2{u0, u1});
    }
    wfrag[m] = fw.v;
    ufrag[m] = fu.v;
  }

  // ---- zero hb pad cols 20..31 (read by fh at q=2,3) ----
#pragma unroll
  for (int k = 0; k < 3; ++k) {
    int i = lane + 64 * k;
    hbl[(i / 12) * HSS + 20 + (i % 12)] = 0.f;
  }

  // ---- stage x(t=0): 240 float2 over the wave's contiguous slab ----
#pragma unroll
  for (int k = 0; k < 4; ++k) {
    int f2 = lane + 64 * k;
    if (f2 < 240) {
      int r = f2 / 15, c = 2 * (f2 % 15);
      *(float2*)&xsl[r * XSS + c] = *(const float2*)(xwave + r * (T * F) + c);
    }
  }

  float cst[5];
#pragma unroll
  for (int m = 0; m < 5; ++m) cst[m] = 0.f;
  float hreg[T][5];   // static indices only (t-loop fully unrolled)
  float2 pf2[4];

#pragma unroll
  for (int t = 0; t < T; ++t) {
    // B-frag of x^T (single-buffer read; t+1 write comes after, program order)
    FragU fx;
    {
      const float* xp = &xsl[r15 * XSS + 8 * q];
      float4 lo = *(const float4*)(xp);
      float4 hi = *(const float4*)(xp + 4);
      fx.h2[0] = __float22bfloat162_rn(float2{lo.x, lo.y});
      fx.h2[1] = __float22bfloat162_rn(float2{lo.z, lo.w});
      fx.h2[2] = __float22bfloat162_rn(float2{hi.x, hi.y});
      fx.h2[3] = __float22bfloat162_rn(float2{hi.z, hi.w});
      if (q == 3) fx.u32[3] = 0x00003F80u;   // bf16x2 {1.0, 0.0} (bias col)
    }

    // T14: issue next-t global loads now; LDS write lands after compute
    if (t + 1 < T) {
#pragma unroll
      for (int k = 0; k < 4; ++k) {
        int f2 = lane + 64 * k;
        if (f2 < 240) {
          int r = f2 / 15, c = 2 * (f2 % 15);
          pf2[k] = *(const float2*)(xwave + r * (T * F) + (t + 1) * F + c);
        }
      }
    }

    f32x4 acc[5];
#pragma unroll
    for (int m = 0; m < 5; ++m)
      acc[m] = __builtin_amdgcn_mfma_f32_16x16x32_bf16(
          wfrag[m], fx.v, f32x4{0.f, 0.f, 0.f, 0.f}, 0, 0, 0);

    if (t > 0) {   // recurrent term (t=0: h==0, matches reference)
      FragU fh;
      const float* hp = &hbl[r15 * HSS + 8 * q];
      float4 lo = *(const float4*)(hp);
      float4 hi = *(const float4*)(hp + 4);
      fh.h2[0] = __float22bfloat162_rn(float2{lo.x, lo.y});
      fh.h2[1] = __float22bfloat162_rn(float2{lo.z, lo.w});
      fh.h2[2] = __float22bfloat162_rn(float2{hi.x, hi.y});
      fh.h2[3] = __float22bfloat162_rn(float2{hi.z, hi.w});
#pragma unroll
      for (int m = 0; m < 5; ++m)
        acc[m] = __builtin_amdgcn_mfma_f32_16x16x32_bf16(
            ufrag[m], fh.v, acc[m], 0, 0, 0);
    }

    // gate math: lane-local; h goes to registers (+hb only if next t needs it)
#pragma unroll
    for (int m = 0; m < 5; ++m) {
      float fg = sig(acc[m][0]);
      float ig = sig(acc[m][1]);
      float og = sig(acc[m][2]);
      float ch = tanh_s(acc[m][3]);
      float cn = fmaf(fg, cst[m], ig * ch);
      cst[m] = cn;
      float hn = og * tanh_s(cn);
      hreg[t][m] = hn;
      if (t + 1 < T) hbl[r15 * HSS + 4 * m + q] = hn;
    }

    // write staged x(t+1) (after this t's fx read — program order)
    if (t + 1 < T) {
#pragma unroll
      for (int k = 0; k < 4; ++k) {
        int f2 = lane + 64 * k;
        if (f2 < 240) {
          int r = f2 / 15, c = 2 * (f2 % 15);
          *(float2*)&xsl[r * XSS + c] = pf2[k];
        }
      }
    }
  }

  // ---- drain: slab reused as hist[16][100] (xs/hb dead from here on) ----
#pragma unroll
  for (int t = 0; t < T; ++t)
#pragma unroll
    for (int m = 0; m < 5; ++m)
      slab[r15 * 100 + t * H + 4 * m + q] = hreg[t][m];

#pragma unroll
  for (int k = 0; k < 7; ++k) {
    int f4 = lane + 64 * k;
    if (f4 < 16 * T * H / 4) {
      int r = f4 / 25, c4 = 4 * (f4 % 25);
      float4 v = *(const float4*)&slab[r * 100 + c4];
      *(float4*)(owave + r * (T * H) + c4) = v;
    }
  }
}

} // namespace

extern "C" void kernel_launch(void* const* d_in, const int* in_sizes, int n_in,
                              void* d_out, int out_size, void* d_ws, size_t ws_size,
                              hipStream_t stream) {
  const float* x  = (const float*)d_in[0];
  const float* wf = (const float*)d_in[1];
  const float* wi = (const float*)d_in[2];
  const float* wo = (const float*)d_in[3];
  const float* wc = (const float*)d_in[4];
  const float* uf = (const float*)d_in[5];
  const float* ui = (const float*)d_in[6];
  const float* uo = (const float*)d_in[7];
  const float* uc = (const float*)d_in[8];
  const float* bf = (const float*)d_in[9];
  const float* bi = (const float*)d_in[10];
  const float* bo = (const float*)d_in[11];
  const float* bc = (const float*)d_in[12];
  float* out = (float*)d_out;

  dim3 block(256);
  dim3 grid(BATCH / BPB);   // 2048 blocks
  hipLaunchKernelGGL(lstm_slab, grid, block, 0, stream,
                     x, wf, wi, wo, wc, uf, ui, uo, uc, bf, bi, bo, bc, out);
}

// Round 9
// 44.450 us; speedup vs baseline: 1.8636x; 1.8636x over previous
//
#include <hip/hip_runtime.h>
#include <hip/hip_bf16.h>

namespace {

constexpr int T = 5, F = 30, H = 20;
constexpr int BATCH = 131072;
constexpr int BPB = 64;     // batch rows per block (16 per wave)
constexpr int XSS = 36;     // xs row stride (dwords): 16B-aligned b128, 2-way banks
constexpr int HSS = 36;     // hb row stride

typedef __attribute__((ext_vector_type(8))) short bf16x8;
typedef __attribute__((ext_vector_type(4))) float f32x4;

union FragU { __hip_bfloat162 h2[4]; unsigned u32[4]; bf16x8 v; };

__device__ __forceinline__ float sig(float v) {
  return __builtin_amdgcn_rcpf(1.0f + __builtin_amdgcn_exp2f(v * -1.44269504f));
}
// tanh(v) = 2*sigmoid(2v) - 1; saturates correctly at +-inf, no NaN paths.
__device__ __forceinline__ float tanh_s(float v) {
  return fmaf(2.0f,
              __builtin_amdgcn_rcpf(1.0f + __builtin_amdgcn_exp2f(v * -2.88539008f)),
              -1.0f);
}

// round-to-nearest-even f32 -> bf16 bits (inputs are tanh-bounded, no NaN/inf)
__device__ __forceinline__ unsigned short f2bf(float f) {
  unsigned u = __float_as_uint(f);
  return (unsigned short)((u + 0x7FFFu + ((u >> 16) & 1u)) >> 16);
}

// ---- setup: pre-pack the 640 MFMA A-fragments into d_ws ----
// item i: lane = i&63, sel = (i>>6)&1 (0=W,1=U), m = i>>7 (0..4).
// W rows hidx = 4*jj + gate; bias folded at k==30 (x virtual col 30 == 1.0).
__global__ void lstm_pack(
    const float* __restrict__ wf, const float* __restrict__ wi,
    const float* __restrict__ wo, const float* __restrict__ wc,
    const float* __restrict__ uf, const float* __restrict__ ui,
    const float* __restrict__ uo, const float* __restrict__ uc,
    const float* __restrict__ bf, const float* __restrict__ bi,
    const float* __restrict__ bo, const float* __restrict__ bc,
    bf16x8* __restrict__ ws)
{
  const int i = blockIdx.x * 256 + threadIdx.x;
  if (i >= 640) return;
  const int lane = i & 63, sel = (i >> 6) & 1, m = i >> 7;
  const int r15 = lane & 15, q = lane >> 4;
  const int gA = r15 & 3, jA = r15 >> 2;
  const int jj = 4 * m + jA;

  const float* Wg = (gA == 0) ? wf : (gA == 1) ? wi : (gA == 2) ? wo : wc;
  const float* Ug = (gA == 0) ? uf : (gA == 1) ? ui : (gA == 2) ? uo : uc;
  const float* Bg = (gA == 0) ? bf : (gA == 1) ? bi : (gA == 2) ? bo : bc;

  FragU fr;
#pragma unroll
  for (int e = 0; e < 4; ++e) {
    const int k0 = 8 * q + 2 * e, k1 = k0 + 1;
    float v0, v1;
    if (sel == 0) {
      v0 = (k0 < F) ? Wg[k0 * H + jj] : (k0 == F ? Bg[jj] : 0.f);
      v1 = (k1 < F) ? Wg[k1 * H + jj] : 0.f;
    } else {
      v0 = (k0 < H) ? Ug[k0 * H + jj] : 0.f;
      v1 = (k1 < H) ? Ug[k1 * H + jj] : 0.f;
    }
    fr.h2[e] = __float22bfloat162_rn(float2{v0, v1});
  }
  ws[(m * 2 + sel) * 64 + lane] = fr.v;   // [m][sel][lane] -> coalesced reads
}

// ---- main: barrier-free, wave-private LDS rows, 5 blocks/CU ----
__global__ __launch_bounds__(256, 5) void lstm_main(
    const float* __restrict__ x,
    const bf16x8* __restrict__ wsfrag,
    float* __restrict__ out)
{
  const int tid  = threadIdx.x;
  const int lane = tid & 63;
  const int wv   = tid >> 6;
  const int r15  = lane & 15;
  const int q    = lane >> 4;
  const int b0   = blockIdx.x * BPB;
  const int w0   = 16 * wv;

  const float* xwave = x + (size_t)(b0 + w0) * (T * F);   // contiguous 9.6 KB
  float*       owave = out + (size_t)(b0 + w0) * (T * H); // contiguous 6.4 KB

  __shared__ __align__(16) float xs[BPB][XSS];            //  9.2 KB
  __shared__ __align__(16) float hb[BPB][HSS];            //  9.2 KB
  __shared__ __align__(8)  unsigned short hist[BPB][100]; // 12.8 KB (bf16 h_t)

  // prologue: 10 coalesced dwordx4 loads replace 80 divergent scalar loads
  bf16x8 wfrag[5], ufrag[5];
#pragma unroll
  for (int m = 0; m < 5; ++m) {
    wfrag[m] = wsfrag[(m * 2 + 0) * 64 + lane];
    ufrag[m] = wsfrag[(m * 2 + 1) * 64 + lane];
  }

  // zero hb pad cols 20..31 (read by fh at q=2,3); wave-private rows
#pragma unroll
  for (int k = 0; k < 3; ++k) {
    int i = lane + 64 * k;
    hb[w0 + i / 12][20 + i % 12] = 0.f;
  }

  // stage x(t=0): r = slot>>4, cslot = slot&15 (15 active of 16), c = 2*cslot
#pragma unroll
  for (int k = 0; k < 4; ++k) {
    int s = lane + 64 * k;
    int r = s >> 4, cs = s & 15;
    if (cs < 15) {
      *(float2*)&xs[w0 + r][2 * cs] = *(const float2*)(xwave + r * (T * F) + 2 * cs);
    }
  }

  float cst[5];
#pragma unroll
  for (int m = 0; m < 5; ++m) cst[m] = 0.f;
  float2 pf2[4];

#pragma unroll
  for (int t = 0; t < T; ++t) {
    // B-frag of x^T (read precedes this t's overwrite -> program order safe)
    FragU fx;
    {
      const float* xp = &xs[w0 + r15][8 * q];
      float4 lo = *(const float4*)(xp);
      float4 hi = *(const float4*)(xp + 4);
      fx.h2[0] = __float22bfloat162_rn(float2{lo.x, lo.y});
      fx.h2[1] = __float22bfloat162_rn(float2{lo.z, lo.w});
      fx.h2[2] = __float22bfloat162_rn(float2{hi.x, hi.y});
      fx.h2[3] = __float22bfloat162_rn(float2{hi.z, hi.w});
      if (q == 3) fx.u32[3] = 0x00003F80u;   // bf16x2 {1.0, 0.0} = bias col 30
    }

    // T14: issue next-t global loads now; LDS write lands after compute
    if (t + 1 < T) {
#pragma unroll
      for (int k = 0; k < 4; ++k) {
        int s = lane + 64 * k;
        int r = s >> 4, cs = s & 15;
        if (cs < 15)
          pf2[k] = *(const float2*)(xwave + r * (T * F) + (t + 1) * F + 2 * cs);
      }
    }

    f32x4 acc[5];
#pragma unroll
    for (int m = 0; m < 5; ++m)
      acc[m] = __builtin_amdgcn_mfma_f32_16x16x32_bf16(
          wfrag[m], fx.v, f32x4{0.f, 0.f, 0.f, 0.f}, 0, 0, 0);

    if (t > 0) {   // recurrent term (t=0: h==0, matches reference)
      FragU fh;
      const float* hp = &hb[w0 + r15][8 * q];
      float4 lo = *(const float4*)(hp);
      float4 hi = *(const float4*)(hp + 4);
      fh.h2[0] = __float22bfloat162_rn(float2{lo.x, lo.y});
      fh.h2[1] = __float22bfloat162_rn(float2{lo.z, lo.w});
      fh.h2[2] = __float22bfloat162_rn(float2{hi.x, hi.y});
      fh.h2[3] = __float22bfloat162_rn(float2{hi.z, hi.w});
#pragma unroll
      for (int m = 0; m < 5; ++m)
        acc[m] = __builtin_amdgcn_mfma_f32_16x16x32_bf16(
            ufrag[m], fh.v, acc[m], 0, 0, 0);
    }

    // gate math: lane-local (acc[m] = f,i,o,c of hidden jj=4m+q, own row)
#pragma unroll
    for (int m = 0; m < 5; ++m) {
      float fg = sig(acc[m][0]);
      float ig = sig(acc[m][1]);
      float og = sig(acc[m][2]);
      float ch = tanh_s(acc[m][3]);
      float cn = fmaf(fg, cst[m], ig * ch);
      cst[m] = cn;
      float hn = og * tanh_s(cn);
      const int jj = 4 * m + q;
      if (t + 1 < T) hb[w0 + r15][jj] = hn;      // next-t recurrent source
      hist[w0 + r15][t * H + jj] = f2bf(hn);     // bf16 history for drain
    }

    // write staged x(t+1) (after this t's fx read — program order)
    if (t + 1 < T) {
#pragma unroll
      for (int k = 0; k < 4; ++k) {
        int s = lane + 64 * k;
        int r = s >> 4, cs = s & 15;
        if (cs < 15) *(float2*)&xs[w0 + r][2 * cs] = pf2[k];
      }
    }
  }

  // drain: wave's contiguous 6.4 KB slab, full-line float4 stores.
  // g in [0,400): dst dword = 4g; src = hist[w0 + g/25][4*(g%25)] (8B-aligned).
#pragma unroll
  for (int k = 0; k < 7; ++k) {
    unsigned g = lane + 64 * k;
    if (g < 400) {
      unsigned r = g / 25u, c4 = 4 * (g % 25u);
      uint2 pv = *(const uint2*)&hist[w0 + r][c4];
      float4 v;
      v.x = __uint_as_float(pv.x << 16);
      v.y = __uint_as_float(pv.x & 0xFFFF0000u);
      v.z = __uint_as_float(pv.y << 16);
      v.w = __uint_as_float(pv.y & 0xFFFF0000u);
      *(float4*)(owave + 4 * g) = v;
    }
  }
}

} // namespace

extern "C" void kernel_launch(void* const* d_in, const int* in_sizes, int n_in,
                              void* d_out, int out_size, void* d_ws, size_t ws_size,
                              hipStream_t stream) {
  const float* x  = (const float*)d_in[0];
  const float* wf = (const float*)d_in[1];
  const float* wi = (const float*)d_in[2];
  const float* wo = (const float*)d_in[3];
  const float* wc = (const float*)d_in[4];
  const float* uf = (const float*)d_in[5];
  const float* ui = (const float*)d_in[6];
  const float* uo = (const float*)d_in[7];
  const float* uc = (const float*)d_in[8];
  const float* bf = (const float*)d_in[9];
  const float* bi = (const float*)d_in[10];
  const float* bo = (const float*)d_in[11];
  const float* bc = (const float*)d_in[12];
  float* out = (float*)d_out;
  bf16x8* ws = (bf16x8*)d_ws;   // needs 10,240 B

  hipLaunchKernelGGL(lstm_pack, dim3(3), dim3(256), 0, stream,
                     wf, wi, wo, wc, uf, ui, uo, uc, bf, bi, bo, bc, ws);
  hipLaunchKernelGGL(lstm_main, dim3(BATCH / BPB), dim3(256), 0, stream,
                     x, ws, out);
}

// Round 10
// 39.845 us; speedup vs baseline: 2.0790x; 1.1156x over previous
//
#include <hip/hip_runtime.h>
#include <hip/hip_bf16.h>

namespace {

constexpr int T = 5, F = 30, H = 20;
constexpr int BATCH = 131072;
constexpr int BPB = 64;    // batch rows per block (16 per wave)
constexpr int XRS = 20;    // xsb row stride in dwords (40 halfwords / 80 B)
constexpr int HRS = 132;   // hist row stride in halfwords (264 B / 66 dwords)

typedef __attribute__((ext_vector_type(8))) short bf16x8;
typedef __attribute__((ext_vector_type(4))) float f32x4;

union Frag16 { uint2 d2[2]; uint4 d4; unsigned u32[4]; bf16x8 v; };
union Pack2 { __hip_bfloat162 h2; unsigned u; };

__device__ __forceinline__ float sig(float v) {
  return __builtin_amdgcn_rcpf(1.0f + __builtin_amdgcn_exp2f(v * -1.44269504f));
}
// tanh(v) = 2*sigmoid(2v) - 1; saturates correctly at +-inf, no NaN paths.
__device__ __forceinline__ float tanh_s(float v) {
  return fmaf(2.0f,
              __builtin_amdgcn_rcpf(1.0f + __builtin_amdgcn_exp2f(v * -2.88539008f)),
              -1.0f);
}
// round-to-nearest-even f32 -> bf16 bits (inputs tanh-bounded, no NaN/inf)
__device__ __forceinline__ unsigned short f2bf(float f) {
  unsigned u = __float_as_uint(f);
  return (unsigned short)((u + 0x7FFFu + ((u >> 16) & 1u)) >> 16);
}

// ---- setup: pre-pack the 640 MFMA A-fragments into d_ws ----
// item i: lane = i&63, sel = (i>>6)&1 (0=W,1=U), m = i>>7 (0..4).
// W rows hidx = 4*jj + gate; bias folded at k==30 (x virtual col 30 == 1.0).
// CRITICAL invariant: U rows k>=20 are ZERO and W rows k=31 are ZERO -- the
// main kernel relies on this to tolerate garbage B-fragment data at k>=20.
__global__ void lstm_pack(
    const float* __restrict__ wf, const float* __restrict__ wi,
    const float* __restrict__ wo, const float* __restrict__ wc,
    const float* __restrict__ uf, const float* __restrict__ ui,
    const float* __restrict__ uo, const float* __restrict__ uc,
    const float* __restrict__ bf, const float* __restrict__ bi,
    const float* __restrict__ bo, const float* __restrict__ bc,
    bf16x8* __restrict__ ws)
{
  const int i = blockIdx.x * 256 + threadIdx.x;
  if (i >= 640) return;
  const int lane = i & 63, sel = (i >> 6) & 1, m = i >> 7;
  const int r15 = lane & 15, q = lane >> 4;
  const int gA = r15 & 3, jA = r15 >> 2;
  const int jj = 4 * m + jA;

  const float* Wg = (gA == 0) ? wf : (gA == 1) ? wi : (gA == 2) ? wo : wc;
  const float* Ug = (gA == 0) ? uf : (gA == 1) ? ui : (gA == 2) ? uo : uc;
  const float* Bg = (gA == 0) ? bf : (gA == 1) ? bi : (gA == 2) ? bo : bc;

  Frag16 fr;
#pragma unroll
  for (int e = 0; e < 4; ++e) {
    const int k0 = 8 * q + 2 * e, k1 = k0 + 1;
    float v0, v1;
    if (sel == 0) {
      v0 = (k0 < F) ? Wg[k0 * H + jj] : (k0 == F ? Bg[jj] : 0.f);
      v1 = (k1 < F) ? Wg[k1 * H + jj] : 0.f;
    } else {
      v0 = (k0 < H) ? Ug[k0 * H + jj] : 0.f;
      v1 = (k1 < H) ? Ug[k1 * H + jj] : 0.f;
    }
    Pack2 p; p.h2 = __float22bfloat162_rn(float2{v0, v1});
    fr.u32[e] = p.u;
  }
  ws[(m * 2 + sel) * 64 + lane] = fr.v;   // [m][sel][lane] -> coalesced reads
}

// ---- main: barrier-free, wave-private LDS rows, 7 blocks/CU (22 KB LDS) ----
__global__ __launch_bounds__(256, 4) void lstm_main(
    const float* __restrict__ x,
    const bf16x8* __restrict__ wsfrag,
    float* __restrict__ out)
{
  const int tid  = threadIdx.x;
  const int lane = tid & 63;
  const int wv   = tid >> 6;
  const int r15  = lane & 15;
  const int q    = lane >> 4;
  const int b0   = blockIdx.x * BPB;
  const int w0   = 16 * wv;

  const float* xwave = x + (size_t)(b0 + w0) * (T * F);   // contiguous 9.6 KB
  float*       owave = out + (size_t)(b0 + w0) * (T * H); // contiguous 6.4 KB

  // xsb: bf16 x tile in fragment layout. Row r: hw k=0..29 = bf16(x), hw30 =
  // 1.0 (bias col), hw31 = 0, hw32..39 pad. 5.1 KB.
  __shared__ __align__(16) unsigned xsb[BPB * XRS];
  // hist: bf16 h history, row layout [t][24] (jj 0..19 + 4 dead slots).
  // Serves BOTH the recurrent fh reads and the final drain. Dead/garbage
  // slots are only ever multiplied by zero U-rows. 16.9 KB.
  __shared__ __align__(16) unsigned short hist[BPB * HRS];

  // prologue: 10 coalesced dwordx4 fragment loads
  bf16x8 wfrag[5], ufrag[5];
#pragma unroll
  for (int m = 0; m < 5; ++m) {
    wfrag[m] = wsfrag[(m * 2 + 0) * 64 + lane];
    ufrag[m] = wsfrag[(m * 2 + 1) * 64 + lane];
  }

  // bias/zero constant dword (hw30=1.0, hw31=0) for all 64 rows, once
  if (tid < BPB) xsb[tid * XRS + 15] = 0x00003F80u;

  // stage x(t=0): slot s: r=s>>4, cs=s&15 (15 of 16 active), cols 2cs,2cs+1
#pragma unroll
  for (int j = 0; j < 4; ++j) {
    int s = lane + 64 * j;
    int r = s >> 4, cs = s & 15;
    if (cs < 15) {
      float2 v = *(const float2*)(xwave + r * (T * F) + 2 * cs);
      Pack2 p; p.h2 = __float22bfloat162_rn(v);
      xsb[(w0 + r) * XRS + cs] = p.u;
    }
  }

  float cst[5];
#pragma unroll
  for (int m = 0; m < 5; ++m) cst[m] = 0.f;
  float2 pf2[4];

#pragma unroll
  for (int t = 0; t < T; ++t) {
    // fx: single b128 from fragment-layout LDS (bias baked in, no cvt)
    Frag16 fx;
    fx.d4 = *(const uint4*)&xsb[(w0 + r15) * XRS + 4 * q];

    // T14: issue next-t global loads now; cvt+LDS-write land after compute
    if (t + 1 < T) {
#pragma unroll
      for (int j = 0; j < 4; ++j) {
        int s = lane + 64 * j;
        int r = s >> 4, cs = s & 15;
        if (cs < 15)
          pf2[j] = *(const float2*)(xwave + r * (T * F) + (t + 1) * F + 2 * cs);
      }
    }

    f32x4 acc[5];
#pragma unroll
    for (int m = 0; m < 5; ++m)
      acc[m] = __builtin_amdgcn_mfma_f32_16x16x32_bf16(
          wfrag[m], fx.v, f32x4{0.f, 0.f, 0.f, 0.f}, 0, 0, 0);

    if (t > 0) {   // recurrent term (t=0: h==0, matches reference)
      // fh straight from hist: hw 24(t-1)+8q.. ; k>=20 slots are garbage but
      // hit zero U-rows. 2x b64 (8B-aligned).
      Frag16 fh;
      const unsigned short* hp = &hist[(w0 + r15) * HRS + 24 * (t - 1) + 8 * q];
      fh.d2[0] = *(const uint2*)(hp);
      fh.d2[1] = *(const uint2*)(hp + 4);
#pragma unroll
      for (int m = 0; m < 5; ++m)
        acc[m] = __builtin_amdgcn_mfma_f32_16x16x32_bf16(
            ufrag[m], fh.v, acc[m], 0, 0, 0);
    }

    // gate math: lane-local (acc[m] = f,i,o,c of hidden jj=4m+q, own row)
#pragma unroll
    for (int m = 0; m < 5; ++m) {
      float fg = sig(acc[m][0]);
      float ig = sig(acc[m][1]);
      float og = sig(acc[m][2]);
      float ch = tanh_s(acc[m][3]);
      float cn = fmaf(fg, cst[m], ig * ch);
      cst[m] = cn;
      float hn = og * tanh_s(cn);
      hist[(w0 + r15) * HRS + 24 * t + 4 * m + q] = f2bf(hn);
    }

    // write staged x(t+1) (after this t's fx read -- program order)
    if (t + 1 < T) {
#pragma unroll
      for (int j = 0; j < 4; ++j) {
        int s = lane + 64 * j;
        int r = s >> 4, cs = s & 15;
        if (cs < 15) {
          Pack2 p; p.h2 = __float22bfloat162_rn(pf2[j]);
          xsb[(w0 + r) * XRS + cs] = p.u;
        }
      }
    }
  }

  // drain: wave's contiguous 6.4 KB out slab, full-line float4 stores.
  // g in [0,400): out dwords 4g..4g+3 = row r=g/25, cols c4..c4+3 (c4=4(g%25));
  // src hw = 24*(c4/20) + c4%20 (never crosses a t-block: 20 % 4 == 0).
#pragma unroll
  for (int k = 0; k < 7; ++k) {
    unsigned g = lane + 64 * k;
    if (g < 400) {
      unsigned r = g / 25u, c4 = 4 * (g % 25u);
      unsigned tb = c4 / 20u, j0 = c4 % 20u;
      uint2 pv = *(const uint2*)&hist[(w0 + r) * HRS + 24 * tb + j0];
      float4 v;
      v.x = __uint_as_float(pv.x << 16);
      v.y = __uint_as_float(pv.x & 0xFFFF0000u);
      v.z = __uint_as_float(pv.y << 16);
      v.w = __uint_as_float(pv.y & 0xFFFF0000u);
      *(float4*)(owave + 4 * g) = v;
    }
  }
}

} // namespace

extern "C" void kernel_launch(void* const* d_in, const int* in_sizes, int n_in,
                              void* d_out, int out_size, void* d_ws, size_t ws_size,
                              hipStream_t stream) {
  const float* x  = (const float*)d_in[0];
  const float* wf = (const float*)d_in[1];
  const float* wi = (const float*)d_in[2];
  const float* wo = (const float*)d_in[3];
  const float* wc = (const float*)d_in[4];
  const float* uf = (const float*)d_in[5];
  const float* ui = (const float*)d_in[6];
  const float* uo = (const float*)d_in[7];
  const float* uc = (const float*)d_in[8];
  const float* bf = (const float*)d_in[9];
  const float* bi = (const float*)d_in[10];
  const float* bo = (const float*)d_in[11];
  const float* bc = (const float*)d_in[12];
  float* out = (float*)d_out;
  bf16x8* ws = (bf16x8*)d_ws;   // needs 10,240 B

  hipLaunchKernelGGL(lstm_pack, dim3(3), dim3(256), 0, stream,
                     wf, wi, wo, wc, uf, ui, uo, uc, bf, bi, bo, bc, ws);
  hipLaunchKernelGGL(lstm_main, dim3(BATCH / BPB), dim3(256), 0, stream,
                     x, ws, out);
}